// Round 4
// baseline (532.770 us; speedup 1.0000x reference)
//
#include <hip/hip_runtime.h>

#define HIDDEN 64
#define NREL 50
#define NPAIR (NREL * NREL)
#define NXCD 8
#define K_INL 2           // inline u16 slots per copy record: {u32 cnt; u16 s[2]} = 8 B
#define K_OVF 16          // shared overflow slots per edge (capacity 8*2+16 = 32 >= max deg ~12)

typedef int   iv2 __attribute__((ext_vector_type(2)));
typedef int   iv4 __attribute__((ext_vector_type(4)));
typedef float fv4 __attribute__((ext_vector_type(4)));

// Physical XCD id of the CU this wave runs on (gfx940+; verified on gfx950).
__device__ __forceinline__ unsigned int get_xcc() {
    unsigned int x;
    asm("s_getreg_b32 %0, hwreg(HW_REG_XCC_ID, 0, 4)" : "=s"(x));
    return x & 7u;
}

// ---------------------------------------------------------------------------
// Kernel 1: precompute tables + u8 relation copy.
//   M2[p][j] = sum_k relu( sum_i pair_p[i] * W_msg[i][k] ) * W_upd[64+k][j]
//   Hc[r][j] = sum_i rel_emb[r][i] * W_upd[i][j]
//   rel8[e]  = (u8)rel[e]
// ---------------------------------------------------------------------------
__global__ void precompute_tables(const float* __restrict__ rel_emb,
                                  const float* __restrict__ W_msg,
                                  const float* __restrict__ W_upd,
                                  const int* __restrict__ rel,
                                  unsigned char* __restrict__ rel8,
                                  int conv_n,
                                  float* __restrict__ M2,
                                  float* __restrict__ Hc) {
    const int p = blockIdx.x;      // 0..2499
    const int j = threadIdx.x;     // 0..63

    for (int i = p * HIDDEN + j; i < conv_n; i += NPAIR * HIDDEN)
        rel8[i] = (unsigned char)rel[i];

    const int ra = p / NREL, rb = p % NREL;
    __shared__ float msg[HIDDEN];
    const float* ha = rel_emb + ra * HIDDEN;
    const float* hb = rel_emb + rb * HIDDEN;

    float acc = 0.f;
    #pragma unroll 8
    for (int i = 0; i < HIDDEN; ++i) acc += ha[i] * W_msg[i * HIDDEN + j];
    #pragma unroll 8
    for (int i = 0; i < HIDDEN; ++i) acc += hb[i] * W_msg[(HIDDEN + i) * HIDDEN + j];
    msg[j] = fmaxf(acc, 0.f);
    __syncthreads();

    float acc2 = 0.f;
    #pragma unroll 8
    for (int k = 0; k < HIDDEN; ++k) acc2 += msg[k] * W_upd[(HIDDEN + k) * HIDDEN + j];
    M2[p * HIDDEN + j] = acc2;

    if (p < NREL) {
        float acc3 = 0.f;
        #pragma unroll 8
        for (int i = 0; i < HIDDEN; ++i) acc3 += rel_emb[p * HIDDEN + i] * W_upd[i * HIDDEN + j];
        Hc[p * HIDDEN + j] = acc3;
    }
}

// ---------------------------------------------------------------------------
// Kernel 2: XCD-privatized record scatter. Each XCD owns a private copy of
// the record array; workgroup-scope atomics execute in the XCD-local L2
// (no sc1 device-coherence round trip to the shared fabric point).
// Copies are disjoint per physical XCC_ID -> atomicity needs only XCD-local
// L2 serialization, which no-sc1 atomics provide.
// Rank >= K_INL spills (rare, ~0.2%/copy) via a device-scope counter.
// ---------------------------------------------------------------------------
__global__ __launch_bounds__(256) void hist_record(
        const unsigned char* __restrict__ rel8,
        const int* __restrict__ edge_ab,
        const int* __restrict__ edge_bc,
        const int* __restrict__ edge_ac,
        unsigned int* __restrict__ recA,      // NXCD copies, stride num_edge*2 u32
        unsigned int* __restrict__ ovf,       // device-scope overflow counters
        unsigned short* __restrict__ recB,    // shared overflow slots
        int num_tri, int num_edge) {
    unsigned int* myA = recA + (size_t)get_xcc() * ((size_t)num_edge * 2);
    const int n8 = num_tri >> 3;
    int i = blockIdx.x * blockDim.x + threadIdx.x;
    const int stride = gridDim.x * blockDim.x;
    for (; i < n8; i += stride) {
        const iv4 a0 = __builtin_nontemporal_load((const iv4*)edge_ab + 2 * i);
        const iv4 a1 = __builtin_nontemporal_load((const iv4*)edge_ab + 2 * i + 1);
        const iv4 b0 = __builtin_nontemporal_load((const iv4*)edge_bc + 2 * i);
        const iv4 b1 = __builtin_nontemporal_load((const iv4*)edge_bc + 2 * i + 1);
        const iv4 c0 = __builtin_nontemporal_load((const iv4*)edge_ac + 2 * i);
        const iv4 c1 = __builtin_nontemporal_load((const iv4*)edge_ac + 2 * i + 1);
        int p[8], c[8];
        #pragma unroll
        for (int k = 0; k < 4; ++k) {
            p[k]     = (int)rel8[a0[k]] * NREL + (int)rel8[b0[k]];
            p[k + 4] = (int)rel8[a1[k]] * NREL + (int)rel8[b1[k]];
            c[k]     = c0[k];
            c[k + 4] = c1[k];
        }
        unsigned int r[8];
        #pragma unroll
        for (int k = 0; k < 8; ++k)
            r[k] = __hip_atomic_fetch_add(myA + (size_t)c[k] * 2, 1u,
                                          __ATOMIC_RELAXED, __HIP_MEMORY_SCOPE_WORKGROUP);
        #pragma unroll
        for (int k = 0; k < 8; ++k) {
            if (r[k] < K_INL) {
                ((unsigned short*)(myA + (size_t)c[k] * 2 + 1))[r[k]] = (unsigned short)p[k];
            } else {
                const unsigned int ro = atomicAdd(&ovf[c[k]], 1u);   // device scope, rare
                if (ro < K_OVF) recB[(size_t)c[k] * K_OVF + ro] = (unsigned short)p[k];
            }
        }
    }
    // tail (num_tri % 8), handled by the last block
    const int rem = num_tri & 7;
    if (rem && blockIdx.x == gridDim.x - 1 && threadIdx.x < rem) {
        const int t = (num_tri & ~7) + threadIdx.x;
        const int p = (int)rel8[edge_ab[t]] * NREL + (int)rel8[edge_bc[t]];
        const size_t cc = (size_t)edge_ac[t];
        const unsigned int r = __hip_atomic_fetch_add(myA + cc * 2, 1u,
                                  __ATOMIC_RELAXED, __HIP_MEMORY_SCOPE_WORKGROUP);
        if (r < K_INL) ((unsigned short*)(myA + cc * 2 + 1))[r] = (unsigned short)p;
        else {
            const unsigned int ro = atomicAdd(&ovf[cc], 1u);
            if (ro < K_OVF) recB[cc * K_OVF + ro] = (unsigned short)p;
        }
    }
}

// ---------------------------------------------------------------------------
// Kernel 3: per-edge merge of the 8 copies + gather-accumulate + fused update.
// 16 lanes per edge: lanes 0-7 each load one copy record (iv2), lane 8 loads
// the overflow count; 16-wide shuffles broadcast to the group. Slot values
// feed M2 gathers (L2-resident table) accumulated into the Hc-initialized row.
// ---------------------------------------------------------------------------
__global__ __launch_bounds__(256) void accumulate_record(
        const unsigned char* __restrict__ rel8,
        const unsigned int* __restrict__ recA,
        const unsigned int* __restrict__ ovf,
        const unsigned short* __restrict__ recB,
        const float* __restrict__ M2,
        const float* __restrict__ Hc,
        float* __restrict__ out, int num_edge) {
    const int sub = threadIdx.x >> 4;   // edge slot within block
    const int l   = threadIdx.x & 15;   // float4 lane within row
    const int estride = gridDim.x * 16;
    const size_t cstride = (size_t)num_edge * 2;
    for (int e = blockIdx.x * 16 + sub; e < num_edge; e += estride) {
        iv2 w = {0, 0};
        int ov = 0;
        if (l < NXCD)
            w = *(const iv2*)(recA + cstride * (size_t)l + (size_t)e * 2);
        else if (l == 8)
            ov = (int)ovf[e];
        ov = __shfl(ov, 8, 16);
        const int re = rel8[e];
        fv4 acc0 = ((const fv4*)(Hc + re * HIDDEN))[l];
        fv4 acc1 = (fv4)0.f;
        #pragma unroll
        for (int k = 0; k < NXCD; ++k) {
            const int cnt = __shfl(w.x, k, 16);
            const int ss  = __shfl(w.y, k, 16);
            if (cnt > 0) acc0 += ((const fv4*)M2)[(ss & 0xFFFF) * 16 + l];
            if (cnt > 1) acc1 += ((const fv4*)M2)[(int)(((unsigned)ss) >> 16) * 16 + l];
        }
        const int no = ov < K_OVF ? ov : K_OVF;
        for (int k = 0; k < no; ++k) {            // rare path (~1.6% of edges)
            const int p = recB[(size_t)e * K_OVF + k];
            acc0 += ((const fv4*)M2)[p * 16 + l];
        }
        fv4 o = acc0 + acc1;
        o.x = fmaxf(o.x, 0.f);
        o.y = fmaxf(o.y, 0.f);
        o.z = fmaxf(o.z, 0.f);
        o.w = fmaxf(o.w, 0.f);
        __builtin_nontemporal_store(o, (fv4*)out + (size_t)e * 16 + l);
    }
}

// --------------------------- fallback (atomic) path ------------------------
__global__ void scatter_tri(const int* __restrict__ rel,
                            const int* __restrict__ edge_ab,
                            const int* __restrict__ edge_bc,
                            const int* __restrict__ edge_ac,
                            const float* __restrict__ M2,
                            float* __restrict__ out, int num_tri) {
    const int lane   = threadIdx.x & 63;
    const int wave   = (int)((blockIdx.x * blockDim.x + threadIdx.x) >> 6);
    const int nwaves = (int)((gridDim.x * blockDim.x) >> 6);
    for (int t = wave; t < num_tri; t += nwaves) {
        const int p = rel[edge_ab[t]] * NREL + rel[edge_bc[t]];
        const float v = M2[p * HIDDEN + lane];
        unsafeAtomicAdd(&out[(size_t)edge_ac[t] * HIDDEN + lane], v);
    }
}

__global__ void finalize(const int* __restrict__ rel,
                         const float* __restrict__ Hc,
                         float* __restrict__ out, int num_edge) {
    const int total = num_edge * (HIDDEN / 4);
    int i = blockIdx.x * blockDim.x + threadIdx.x;
    const int stride = gridDim.x * blockDim.x;
    for (; i < total; i += stride) {
        const int e = i >> 4;
        const int q = i & 15;
        float4 a = ((const float4*)out)[i];
        float4 h = ((const float4*)(Hc + rel[e] * HIDDEN))[q];
        float4 o;
        o.x = fmaxf(a.x + h.x, 0.f);
        o.y = fmaxf(a.y + h.y, 0.f);
        o.z = fmaxf(a.z + h.z, 0.f);
        o.w = fmaxf(a.w + h.w, 0.f);
        ((float4*)out)[i] = o;
    }
}
// ---------------------------------------------------------------------------

extern "C" void kernel_launch(void* const* d_in, const int* in_sizes, int n_in,
                              void* d_out, int out_size, void* d_ws, size_t ws_size,
                              hipStream_t stream) {
    const float* rel_emb = (const float*)d_in[0];
    const float* W_msg   = (const float*)d_in[1];
    const float* W_upd   = (const float*)d_in[2];
    const int* rel     = (const int*)d_in[5];
    const int* edge_ab = (const int*)d_in[6];
    const int* edge_bc = (const int*)d_in[7];
    const int* edge_ac = (const int*)d_in[8];
    float* out = (float*)d_out;

    const int num_edge = in_sizes[5];
    const int num_tri  = in_sizes[6];

    // ---- workspace layout (256B-aligned offsets) ----
    char* ws = (char*)d_ws;
    size_t off = 0;
    auto alloc = [&](size_t bytes) { char* p = ws + off; off = (off + bytes + 255) & ~(size_t)255; return p; };
    float*          M2   = (float*)alloc((size_t)NPAIR * HIDDEN * 4);            // 640 KB
    float*          Hc   = (float*)alloc((size_t)NREL * HIDDEN * 4);             // 12.8 KB
    unsigned char*  rel8 = (unsigned char*)alloc((size_t)num_edge);              // 1 MB
    unsigned int*   recA = (unsigned int*)alloc((size_t)num_edge * 8 * NXCD);    // 64 MB
    unsigned int*   ovf  = (unsigned int*)alloc((size_t)num_edge * 4);           // 4 MB
    unsigned short* recB = (unsigned short*)alloc((size_t)num_edge * K_OVF * 2); // 32 MB
    const size_t required = off;

    const bool fast = (ws_size >= required);

    if (fast) {
        hipMemsetAsync(recA, 0, (size_t)num_edge * 8 * NXCD, stream);
        hipMemsetAsync(ovf, 0, (size_t)num_edge * 4, stream);
        precompute_tables<<<NPAIR, HIDDEN, 0, stream>>>(rel_emb, W_msg, W_upd,
                                                        rel, rel8, num_edge, M2, Hc);
        const int n8 = num_tri >> 3;
        int hblocks = (n8 + 255) / 256;
        if (hblocks < 1) hblocks = 1;
        hist_record<<<hblocks, 256, 0, stream>>>(rel8, edge_ab, edge_bc, edge_ac,
                                                 recA, ovf, recB, num_tri, num_edge);
        int ablocks = (num_edge + 15) / 16;
        if (ablocks > 16384) ablocks = 16384;
        accumulate_record<<<ablocks, 256, 0, stream>>>(rel8, recA, ovf, recB, M2, Hc,
                                                       out, num_edge);
    } else {
        // ---- fallback: atomic scatter path (needs only M2 + Hc) ----
        precompute_tables<<<NPAIR, HIDDEN, 0, stream>>>(rel_emb, W_msg, W_upd,
                                                        rel, (unsigned char*)d_ws, 0, M2, Hc);
        hipMemsetAsync(d_out, 0, (size_t)out_size * sizeof(float), stream);
        scatter_tri<<<8192, 256, 0, stream>>>(rel, edge_ab, edge_bc, edge_ac, M2, out, num_tri);
        const int total4 = num_edge * (HIDDEN / 4);
        int fin_blocks = (total4 + 255) / 256;
        if (fin_blocks > 65535 * 8) fin_blocks = 65535 * 8;
        finalize<<<fin_blocks, 256, 0, stream>>>(rel, Hc, out, num_edge);
    }
}

// Round 5
// 465.371 us; speedup vs baseline: 1.1448x; 1.1448x over previous
//
#include <hip/hip_runtime.h>

#define HIDDEN 64
#define NREL 50
#define NPAIR (NREL * NREL)
#define BEDGE 64          // edges per bucket
#define CAP 512           // bucket capacity (Poisson mean 128; P(>512) ~ 0)

typedef int   iv4 __attribute__((ext_vector_type(4)));
typedef float fv4 __attribute__((ext_vector_type(4)));

// ---------------------------------------------------------------------------
// Kernel 1: precompute tables + u8 relation copy.
//   M2[p][j] = sum_k relu( sum_i pair_p[i] * W_msg[i][k] ) * W_upd[64+k][j]
//   Hc[r][j] = sum_i rel_emb[r][i] * W_upd[i][j]
//   rel8[e]  = (u8)rel[e]
// ---------------------------------------------------------------------------
__global__ void precompute_tables(const float* __restrict__ rel_emb,
                                  const float* __restrict__ W_msg,
                                  const float* __restrict__ W_upd,
                                  const int* __restrict__ rel,
                                  unsigned char* __restrict__ rel8,
                                  int conv_n,
                                  float* __restrict__ M2,
                                  float* __restrict__ Hc) {
    const int p = blockIdx.x;      // 0..2499
    const int j = threadIdx.x;     // 0..63

    for (int i = p * HIDDEN + j; i < conv_n; i += NPAIR * HIDDEN)
        rel8[i] = (unsigned char)rel[i];

    const int ra = p / NREL, rb = p % NREL;
    __shared__ float msg[HIDDEN];
    const float* ha = rel_emb + ra * HIDDEN;
    const float* hb = rel_emb + rb * HIDDEN;

    float acc = 0.f;
    #pragma unroll 8
    for (int i = 0; i < HIDDEN; ++i) acc += ha[i] * W_msg[i * HIDDEN + j];
    #pragma unroll 8
    for (int i = 0; i < HIDDEN; ++i) acc += hb[i] * W_msg[(HIDDEN + i) * HIDDEN + j];
    msg[j] = fmaxf(acc, 0.f);
    __syncthreads();

    float acc2 = 0.f;
    #pragma unroll 8
    for (int k = 0; k < HIDDEN; ++k) acc2 += msg[k] * W_upd[(HIDDEN + k) * HIDDEN + j];
    M2[p * HIDDEN + j] = acc2;

    if (p < NREL) {
        float acc3 = 0.f;
        #pragma unroll 8
        for (int i = 0; i < HIDDEN; ++i) acc3 += rel_emb[p * HIDDEN + i] * W_upd[i * HIDDEN + j];
        Hc[p * HIDDEN + j] = acc3;
    }
}

// ---------------------------------------------------------------------------
// Kernel 2: radix partition. bucket = ac>>6 -> atomics hit only NB=~16K
// counters (64 KB, resident at the coherence point: pure pipelined atomic
// throughput, no cold-line thrash). key packs (p, ac&63) in 18 bits.
// Slot index comes from the atomic's return; capacity clamp is statistical
// overkill (mean 128 vs CAP 512). 8 triangles/thread for atomic MLP.
// ---------------------------------------------------------------------------
__global__ __launch_bounds__(256) void partition_tri(
        const unsigned char* __restrict__ rel8,
        const int* __restrict__ edge_ab,
        const int* __restrict__ edge_bc,
        const int* __restrict__ edge_ac,
        unsigned int* __restrict__ cur,       // NB counters
        unsigned int* __restrict__ buf,       // NB * CAP keys
        int num_tri) {
    const int n8 = num_tri >> 3;
    int i = blockIdx.x * blockDim.x + threadIdx.x;
    const int stride = gridDim.x * blockDim.x;
    for (; i < n8; i += stride) {
        const iv4 a0 = __builtin_nontemporal_load((const iv4*)edge_ab + 2 * i);
        const iv4 a1 = __builtin_nontemporal_load((const iv4*)edge_ab + 2 * i + 1);
        const iv4 b0 = __builtin_nontemporal_load((const iv4*)edge_bc + 2 * i);
        const iv4 b1 = __builtin_nontemporal_load((const iv4*)edge_bc + 2 * i + 1);
        const iv4 c0 = __builtin_nontemporal_load((const iv4*)edge_ac + 2 * i);
        const iv4 c1 = __builtin_nontemporal_load((const iv4*)edge_ac + 2 * i + 1);
        int p[8], c[8];
        #pragma unroll
        for (int k = 0; k < 4; ++k) {
            p[k]     = (int)rel8[a0[k]] * NREL + (int)rel8[b0[k]];
            p[k + 4] = (int)rel8[a1[k]] * NREL + (int)rel8[b1[k]];
            c[k]     = c0[k];
            c[k + 4] = c1[k];
        }
        unsigned int r[8];
        #pragma unroll
        for (int k = 0; k < 8; ++k)
            r[k] = atomicAdd(&cur[c[k] >> 6], 1u);
        #pragma unroll
        for (int k = 0; k < 8; ++k)
            if (r[k] < CAP)
                buf[(size_t)(c[k] >> 6) * CAP + r[k]] =
                    ((unsigned int)p[k] << 6) | ((unsigned int)c[k] & 63u);
    }
    // tail (num_tri % 8), handled by the last block
    const int rem = num_tri & 7;
    if (rem && blockIdx.x == gridDim.x - 1 && threadIdx.x < rem) {
        const int t = (num_tri & ~7) + threadIdx.x;
        const int p = (int)rel8[edge_ab[t]] * NREL + (int)rel8[edge_bc[t]];
        const int c = edge_ac[t];
        const unsigned int r = atomicAdd(&cur[c >> 6], 1u);
        if (r < CAP)
            buf[(size_t)(c >> 6) * CAP + r] =
                ((unsigned int)p << 6) | ((unsigned int)c & 63u);
    }
}

// ---------------------------------------------------------------------------
// Kernel 3: one block per bucket. Coalesced-load the bucket's keys into LDS;
// 16 groups of 16 lanes each own 4 of the bucket's 64 edges. Per edge:
// ballot-scan the LDS keys (16 at a time), broadcast matching p via shfl,
// all 16 lanes gather the M2 float4 row slice. Fused Hc + ReLU + NT store.
// No global atomics, no per-edge records, exact counts (no overflow path).
// ---------------------------------------------------------------------------
__global__ __launch_bounds__(256) void accumulate_bucket(
        const unsigned char* __restrict__ rel8,
        const unsigned int* __restrict__ cur,
        const unsigned int* __restrict__ buf,
        const float* __restrict__ M2,
        const float* __restrict__ Hc,
        float* __restrict__ out, int num_edge) {
    __shared__ unsigned int lk[CAP];
    const int b = blockIdx.x;                 // bucket id
    const unsigned int craw = cur[b];
    const int cnt = craw < CAP ? (int)craw : CAP;
    for (int t = threadIdx.x; t < cnt; t += 256)
        lk[t] = buf[(size_t)b * CAP + t];
    __syncthreads();

    const int g     = threadIdx.x >> 4;       // group 0..15
    const int l     = threadIdx.x & 15;       // lane in group (float4 slice)
    const int shift = threadIdx.x & 48;       // group's 16-bit slice of wave ballot

    for (int le = g; le < BEDGE; le += 16) {  // 4 local edges per group
        const int e = b * BEDGE + le;
        if (e >= num_edge) continue;
        const int re = rel8[e];
        fv4 acc = ((const fv4*)(Hc + re * HIDDEN))[l];
        for (int base = 0; base < cnt; base += 16) {
            const int idx = base + l;
            const unsigned int key = (idx < cnt) ? lk[idx] : 0u;
            const bool m = (idx < cnt) && ((int)(key & 63u) == le);
            const unsigned long long bal = __ballot(m);
            unsigned int mask = (unsigned int)((bal >> shift) & 0xFFFFull);
            while (mask) {
                const int bit = __ffs(mask) - 1;
                mask &= mask - 1;
                const int p = __shfl((int)(key >> 6), bit, 16);
                acc += ((const fv4*)M2)[p * 16 + l];
            }
        }
        fv4 o = acc;
        o.x = fmaxf(o.x, 0.f);
        o.y = fmaxf(o.y, 0.f);
        o.z = fmaxf(o.z, 0.f);
        o.w = fmaxf(o.w, 0.f);
        __builtin_nontemporal_store(o, (fv4*)out + (size_t)e * 16 + l);
    }
}

// --------------------------- fallback (atomic) path ------------------------
__global__ void scatter_tri(const int* __restrict__ rel,
                            const int* __restrict__ edge_ab,
                            const int* __restrict__ edge_bc,
                            const int* __restrict__ edge_ac,
                            const float* __restrict__ M2,
                            float* __restrict__ out, int num_tri) {
    const int lane   = threadIdx.x & 63;
    const int wave   = (int)((blockIdx.x * blockDim.x + threadIdx.x) >> 6);
    const int nwaves = (int)((gridDim.x * blockDim.x) >> 6);
    for (int t = wave; t < num_tri; t += nwaves) {
        const int p = rel[edge_ab[t]] * NREL + rel[edge_bc[t]];
        const float v = M2[p * HIDDEN + lane];
        unsafeAtomicAdd(&out[(size_t)edge_ac[t] * HIDDEN + lane], v);
    }
}

__global__ void finalize(const int* __restrict__ rel,
                         const float* __restrict__ Hc,
                         float* __restrict__ out, int num_edge) {
    const int total = num_edge * (HIDDEN / 4);
    int i = blockIdx.x * blockDim.x + threadIdx.x;
    const int stride = gridDim.x * blockDim.x;
    for (; i < total; i += stride) {
        const int e = i >> 4;
        const int q = i & 15;
        float4 a = ((const float4*)out)[i];
        float4 h = ((const float4*)(Hc + rel[e] * HIDDEN))[q];
        float4 o;
        o.x = fmaxf(a.x + h.x, 0.f);
        o.y = fmaxf(a.y + h.y, 0.f);
        o.z = fmaxf(a.z + h.z, 0.f);
        o.w = fmaxf(a.w + h.w, 0.f);
        ((float4*)out)[i] = o;
    }
}
// ---------------------------------------------------------------------------

extern "C" void kernel_launch(void* const* d_in, const int* in_sizes, int n_in,
                              void* d_out, int out_size, void* d_ws, size_t ws_size,
                              hipStream_t stream) {
    const float* rel_emb = (const float*)d_in[0];
    const float* W_msg   = (const float*)d_in[1];
    const float* W_upd   = (const float*)d_in[2];
    const int* rel     = (const int*)d_in[5];
    const int* edge_ab = (const int*)d_in[6];
    const int* edge_bc = (const int*)d_in[7];
    const int* edge_ac = (const int*)d_in[8];
    float* out = (float*)d_out;

    const int num_edge = in_sizes[5];
    const int num_tri  = in_sizes[6];
    const int NB = (num_edge + BEDGE - 1) / BEDGE;   // buckets (16384 for 1M)

    // ---- workspace layout (256B-aligned offsets) ----
    char* ws = (char*)d_ws;
    size_t off = 0;
    auto alloc = [&](size_t bytes) { char* p = ws + off; off = (off + bytes + 255) & ~(size_t)255; return p; };
    float*         M2   = (float*)alloc((size_t)NPAIR * HIDDEN * 4);      // 640 KB
    float*         Hc   = (float*)alloc((size_t)NREL * HIDDEN * 4);       // 12.8 KB
    unsigned char* rel8 = (unsigned char*)alloc((size_t)num_edge);        // 1 MB
    unsigned int*  cur  = (unsigned int*)alloc((size_t)NB * 4);           // 64 KB
    unsigned int*  buf  = (unsigned int*)alloc((size_t)NB * CAP * 4);     // 32 MB (never memset)
    const size_t required = off;

    const bool fast = (ws_size >= required);

    if (fast) {
        hipMemsetAsync(cur, 0, (size_t)NB * 4, stream);
        precompute_tables<<<NPAIR, HIDDEN, 0, stream>>>(rel_emb, W_msg, W_upd,
                                                        rel, rel8, num_edge, M2, Hc);
        const int n8 = num_tri >> 3;
        int pblocks = (n8 + 255) / 256;
        if (pblocks < 1) pblocks = 1;
        partition_tri<<<pblocks, 256, 0, stream>>>(rel8, edge_ab, edge_bc, edge_ac,
                                                   cur, buf, num_tri);
        accumulate_bucket<<<NB, 256, 0, stream>>>(rel8, cur, buf, M2, Hc,
                                                  out, num_edge);
    } else {
        // ---- fallback: atomic scatter path (needs only M2 + Hc) ----
        precompute_tables<<<NPAIR, HIDDEN, 0, stream>>>(rel_emb, W_msg, W_upd,
                                                        rel, (unsigned char*)d_ws, 0, M2, Hc);
        hipMemsetAsync(d_out, 0, (size_t)out_size * sizeof(float), stream);
        scatter_tri<<<8192, 256, 0, stream>>>(rel, edge_ab, edge_bc, edge_ac, M2, out, num_tri);
        const int total4 = num_edge * (HIDDEN / 4);
        int fin_blocks = (total4 + 255) / 256;
        if (fin_blocks > 65535 * 8) fin_blocks = 65535 * 8;
        finalize<<<fin_blocks, 256, 0, stream>>>(rel, Hc, out, num_edge);
    }
}